// Round 2
// baseline (2343.048 us; speedup 1.0000x reference)
//
#include <hip/hip_runtime.h>

// ---------------- problem constants ----------------
#define NUSER 200000
#define NPROD 100000
#define NCAT    2000
#define NQRY   50000
#define EBUYS  500000
#define ESEARCH 300000
#define EMATCH  300000
#define EIN     100000

// type ids: 0=user 1=product 2=category 3=query
// relations t=0..7 (weight-stack index):
//  t0 user->product, t1 product->user, t2 user->query, t3 query->user,
//  t4 query->product, t5 product->query, t6 product->category, t7 category->product
// per-dst relation slots (must match wt_build's relsD):
//  user: {t1,t3}  product: {t0,t4,t7}  category: {t6}  query: {t2,t5}

// ---------------- CSR build ----------------
__global__ __launch_bounds__(256) void count_kernel(const int* __restrict__ dst, int E,
                                                    int* __restrict__ cnt) {
    int i = blockIdx.x * 256 + threadIdx.x;
    if (i < E) atomicAdd(&cnt[dst[i]], 1);
}

__global__ __launch_bounds__(256) void scan_partial(const int* __restrict__ cnt, int n,
                                                    int* __restrict__ bsums) {
    __shared__ int sd[256];
    int base = blockIdx.x * 4096;
    int s = 0;
    for (int j = threadIdx.x; j < 4096; j += 256) {
        int idx = base + j;
        s += (idx < n) ? cnt[idx] : 0;
    }
    sd[threadIdx.x] = s;
    __syncthreads();
    for (int st = 128; st > 0; st >>= 1) {
        if (threadIdx.x < st) sd[threadIdx.x] += sd[threadIdx.x + st];
        __syncthreads();
    }
    if (threadIdx.x == 0) bsums[blockIdx.x] = sd[0];
}

__global__ __launch_bounds__(64) void scan_bsums(int* __restrict__ bs, int nb) {
    int lane = threadIdx.x;
    int orig = (lane < nb) ? bs[lane] : 0;
    int v = orig;
    for (int off = 1; off < 64; off <<= 1) {
        int t = __shfl_up(v, off);
        if (lane >= off) v += t;
    }
    if (lane < nb) bs[lane] = v - orig;  // exclusive
}

__global__ __launch_bounds__(256) void scan_final(const int* __restrict__ cnt, int n,
                                                  const int* __restrict__ bsums,
                                                  int* __restrict__ offs) {
    __shared__ int tsum[256];
    int base = blockIdx.x * 4096;
    int tid = threadIdx.x;
    int local[16];
    int s = 0;
#pragma unroll
    for (int j = 0; j < 16; ++j) {
        int idx = base + tid * 16 + j;
        int v = (idx < n) ? cnt[idx] : 0;
        s += v;
        local[j] = s;
    }
    tsum[tid] = s;
    __syncthreads();
    int v = s;
    for (int off = 1; off < 256; off <<= 1) {
        int t = (tid >= off) ? tsum[tid - off] : 0;
        __syncthreads();
        v += t;
        tsum[tid] = v;
        __syncthreads();
    }
    int tpre = v - s;
    int bpre = bsums[blockIdx.x];
#pragma unroll
    for (int j = 0; j < 16; ++j) {
        int idx = base + tid * 16 + j;
        if (idx < n) offs[idx + 1] = bpre + tpre + local[j];
    }
    if (blockIdx.x == 0 && tid == 0) offs[0] = 0;
}

__global__ __launch_bounds__(256) void fill_kernel(const int* __restrict__ src,
                                                   const int* __restrict__ dst,
                                                   const float* __restrict__ w, int E,
                                                   const int* __restrict__ offs,
                                                   int* __restrict__ fill,
                                                   int* __restrict__ csr_src,
                                                   float* __restrict__ csr_w) {
    int i = blockIdx.x * 256 + threadIdx.x;
    if (i >= E) return;
    int d = dst[i];
    int slot = offs[d] + atomicAdd(&fill[d], 1);
    csr_src[slot] = src[i];
    csr_w[slot] = w[i];
}

// ---------------- f32 -> bf16 hi/lo split helpers ----------------
// hi = truncated top 16 bits (exact bf16); lo = bf16(trunc) of residual.
// a ~= hi + lo with relative error ~2^-16; dropped lo*lo term in the GEMM is
// ~2^-16 relative => result is f32-equivalent for this problem's magnitudes.
__device__ __forceinline__ unsigned pk_hi(float a, float b) {
    return (__float_as_uint(b) & 0xffff0000u) | (__float_as_uint(a) >> 16);
}
__device__ __forceinline__ float f32_trunc(float a) {
    return __uint_as_float(__float_as_uint(a) & 0xffff0000u);
}

typedef short bf16x8 __attribute__((ext_vector_type(8)));
typedef float f32x4 __attribute__((ext_vector_type(4)));

__device__ __forceinline__ bf16x8 pack_hi8(const float4& a, const float4& b) {
    union { unsigned u[4]; bf16x8 v; } r;
    r.u[0] = pk_hi(a.x, a.y);
    r.u[1] = pk_hi(a.z, a.w);
    r.u[2] = pk_hi(b.x, b.y);
    r.u[3] = pk_hi(b.z, b.w);
    return r.v;
}
__device__ __forceinline__ bf16x8 pack_lo8(const float4& a, const float4& b) {
    union { unsigned u[4]; bf16x8 v; } r;
    r.u[0] = pk_hi(a.x - f32_trunc(a.x), a.y - f32_trunc(a.y));
    r.u[1] = pk_hi(a.z - f32_trunc(a.z), a.w - f32_trunc(a.w));
    r.u[2] = pk_hi(b.x - f32_trunc(b.x), b.y - f32_trunc(b.y));
    r.u[3] = pk_hi(b.z - f32_trunc(b.z), b.w - f32_trunc(b.w));
    return r.v;
}

// ---------------- fused weight build ----------------
// Produces bf16 hi/lo planes of the concat-K B matrix in N-MAJOR layout:
//   WH/WL[(l,d) base + n*K_d + s*128 + in], K_d = (1+nrel_d)*128.
// N-major B == original W row-major (B[k][n] = W[n][in]) -> no transpose needed.
// Block 0 (s=0) is sum_t Wl[t]; block s>=1 is Wr[rels[s-1]].
// Also writes bsum[(l*4+d)*128].
__global__ __launch_bounds__(256) void wt_build(const float* __restrict__ W1_l,
                                                const float* __restrict__ b1,
                                                const float* __restrict__ W1_r,
                                                const float* __restrict__ W2_l,
                                                const float* __restrict__ b2,
                                                const float* __restrict__ W2_r,
                                                unsigned short* __restrict__ WH,
                                                unsigned short* __restrict__ WL,
                                                float* __restrict__ bsum) {
    const int relsD[4][3] = {{1, 3, -1}, {0, 4, 7}, {6, -1, -1}, {2, 5, -1}};
    const int nrelD[4] = {2, 3, 1, 2};
    const int pre[4] = {0, 49152, 114688, 147456};  // elements, per-layer prefix
    int bid = blockIdx.x;
    int l = bid / 12, r = bid % 12;
    int d, s;
    if (r < 3) { d = 0; s = r; }
    else if (r < 7) { d = 1; s = r - 3; }
    else if (r < 9) { d = 2; s = r - 7; }
    else { d = 3; s = r - 9; }
    const float* Wl = l ? W2_l : W1_l;
    const float* Wr = l ? W2_r : W1_r;
    const float* bb = l ? b2 : b1;
    int K = (1 + nrelD[d]) * 128;
    size_t base = (size_t)l * 196608 + pre[d];
    if (s == 0 && threadIdx.x < 128) {
        float acc = 0.f;
        for (int j = 0; j < nrelD[d]; ++j) acc += bb[relsD[d][j] * 128 + threadIdx.x];
        bsum[(l * 4 + d) * 128 + threadIdx.x] = acc;
    }
    // 128 n x 128 in elements; 8-elem chunks: 2048 chunks / 256 threads = 8 iters
    for (int p = 0; p < 8; ++p) {
        int c = threadIdx.x + p * 256;
        int n = c >> 4, ic = (c & 15) * 8;
        float e[8];
        if (s == 0) {
#pragma unroll
            for (int q = 0; q < 8; ++q) e[q] = 0.f;
            for (int j = 0; j < nrelD[d]; ++j) {
                const float* wsrc = Wl + relsD[d][j] * 16384 + n * 128 + ic;
#pragma unroll
                for (int q = 0; q < 8; ++q) e[q] += wsrc[q];
            }
        } else {
            const float* wsrc = Wr + relsD[d][s - 1] * 16384 + n * 128 + ic;
#pragma unroll
            for (int q = 0; q < 8; ++q) e[q] = wsrc[q];
        }
        uint4 hi, lo;
        hi.x = pk_hi(e[0], e[1]); hi.y = pk_hi(e[2], e[3]);
        hi.z = pk_hi(e[4], e[5]); hi.w = pk_hi(e[6], e[7]);
        float lv[8];
#pragma unroll
        for (int q = 0; q < 8; ++q) lv[q] = e[q] - f32_trunc(e[q]);
        lo.x = pk_hi(lv[0], lv[1]); lo.y = pk_hi(lv[2], lv[3]);
        lo.z = pk_hi(lv[4], lv[5]); lo.w = pk_hi(lv[6], lv[7]);
        size_t go = base + (size_t)n * K + s * 128 + ic;
        *(uint4*)(WH + go) = hi;
        *(uint4*)(WL + go) = lo;
    }
}

// ---------------- CSR gather-reduce (scatter-mean) into concat-slot layout ----------
// One 64-lane wave per dst row (float2 per lane => 128 floats). Wave-uniform row =>
// CSR index/weight loads are scalar; edge loop unrolled x4 with 4 independent
// accumulators for gather MLP.
__global__ __launch_bounds__(256) void agg_kernel(const float* __restrict__ X, int ldx,
                                                  const int* __restrict__ offs,
                                                  const int* __restrict__ csr_src,
                                                  const float* __restrict__ csr_w,
                                                  float* __restrict__ out, int ldo,
                                                  int n_dst) {
    int row = blockIdx.x * 4 + (threadIdx.x >> 6);
    if (row >= n_dst) return;
    int lane = threadIdx.x & 63;
    int b = offs[row], e = offs[row + 1];
    float2 a0 = {0.f, 0.f}, a1 = {0.f, 0.f}, a2 = {0.f, 0.f}, a3 = {0.f, 0.f};
    int i = b;
    for (; i + 4 <= e; i += 4) {
        int s0 = csr_src[i + 0], s1 = csr_src[i + 1];
        int s2 = csr_src[i + 2], s3 = csr_src[i + 3];
        float w0 = csr_w[i + 0], w1 = csr_w[i + 1];
        float w2 = csr_w[i + 2], w3 = csr_w[i + 3];
        float2 v0 = *(const float2*)(X + (size_t)s0 * ldx + lane * 2);
        float2 v1 = *(const float2*)(X + (size_t)s1 * ldx + lane * 2);
        float2 v2 = *(const float2*)(X + (size_t)s2 * ldx + lane * 2);
        float2 v3 = *(const float2*)(X + (size_t)s3 * ldx + lane * 2);
        a0.x += w0 * v0.x; a0.y += w0 * v0.y;
        a1.x += w1 * v1.x; a1.y += w1 * v1.y;
        a2.x += w2 * v2.x; a2.y += w2 * v2.y;
        a3.x += w3 * v3.x; a3.y += w3 * v3.y;
    }
    for (; i < e; ++i) {
        int s = csr_src[i];
        float w = csr_w[i];
        float2 v = *(const float2*)(X + (size_t)s * ldx + lane * 2);
        a0.x += w * v.x; a0.y += w * v.y;
    }
    float inv = (e > b) ? 1.f / (float)(e - b) : 0.f;
    float2 r;
    r.x = (a0.x + a1.x + a2.x + a3.x) * inv;
    r.y = (a0.y + a1.y + a2.y + a3.y) * inv;
    *(float2*)(out + (size_t)row * ldo + lane * 2) = r;
}

// ---------------- fused concat-K MFMA GEMM: Y = relu?([self|agg] @ W^T + bias) ------
// Split-bf16 (hi/lo) f32 emulation on v_mfma_f32_16x16x32_bf16:
//   C = Ah*Bh + Ah*Bl + Al*Bh  (f32 accumulate; dropped Al*Bl ~ 2^-16 rel)
// NO LDS, NO BARRIERS: A has zero cross-wave reuse (each wave owns its 32 rows), so
// each lane loads its A fragment (8 consecutive f32) straight from global — the wave
// collectively reads 16 rows x 128 B contiguous (fully coalesced). B (<=196 KB,
// shared by every block) is L1/L2-resident and loaded as 16-B fragments directly.
// Explicit reg pipeline (T14): issue tile t+1's A loads, run tile t's 96 MFMAs,
// then convert — HBM latency hides under compute; waves free-run (no barrier drain).
__global__ __launch_bounds__(256, 2) void gemm_fused(const float* __restrict__ Xself, int lds_,
                                                     const float* __restrict__ Xagg, int lda_,
                                                     const unsigned short* __restrict__ WH,
                                                     const unsigned short* __restrict__ WL,
                                                     const float* __restrict__ bias,
                                                     float* __restrict__ Y, int ldy,
                                                     int M, int K, int relu) {
    int tid = threadIdx.x;
    int lane = tid & 63;
    int wave = tid >> 6;  // 0..3
    int m0 = blockIdx.x * 128;
    int ln = lane & 15;
    int kq = (lane >> 4) * 8;         // lane's k-offset within a 32-k step
    int rowA = wave * 32 + ln;        // tile-row for f=0; f=1 adds 16

    f32x4 acc[2][8] = {};  // [m-frag][n-frag]

    float bv[8];
#pragma unroll
    for (int g = 0; g < 8; ++g) bv[g] = bias[g * 16 + ln];

    // A loads for one 64-k tile: per (f, ks): 2x float4 at row m0+rowA+f*16,
    // col kc0 + ks*32 + kq. Layout in Af[]: [(f*2+ks)*2 + half].
    auto ldA = [&](int kt, float4* Af) {
        const float* Xsrc;
        int ldx, kc0;
        if (kt < 128) { Xsrc = Xself; ldx = lds_; kc0 = kt; }
        else { Xsrc = Xagg; ldx = lda_; kc0 = kt - 128; }
#pragma unroll
        for (int f = 0; f < 2; ++f) {
            int gm = m0 + rowA + f * 16;
            const float* pr = Xsrc + (size_t)gm * ldx + kc0 + kq;
#pragma unroll
            for (int ks = 0; ks < 2; ++ks) {
                float4 v0 = {0.f, 0.f, 0.f, 0.f}, v1 = {0.f, 0.f, 0.f, 0.f};
                if (gm < M) {
                    v0 = *(const float4*)(pr + ks * 32);
                    v1 = *(const float4*)(pr + ks * 32 + 4);
                }
                Af[(f * 2 + ks) * 2 + 0] = v0;
                Af[(f * 2 + ks) * 2 + 1] = v1;
            }
        }
    };
    auto cvtA = [&](const float4* Af, bf16x8* ah, bf16x8* al) {
#pragma unroll
        for (int j = 0; j < 4; ++j) {
            ah[j] = pack_hi8(Af[j * 2], Af[j * 2 + 1]);
            al[j] = pack_lo8(Af[j * 2], Af[j * 2 + 1]);
        }
    };
    auto compute = [&](int kt, const bf16x8* ah, const bf16x8* al) {
        size_t nb = (size_t)ln * K + kt + kq;
#pragma unroll
        for (int ks = 0; ks < 2; ++ks) {
#pragma unroll
            for (int g = 0; g < 8; ++g) {
                size_t off = nb + (size_t)g * 16 * K + ks * 32;
                bf16x8 bh = *(const bf16x8*)(WH + off);
                bf16x8 bl = *(const bf16x8*)(WL + off);
#pragma unroll
                for (int f = 0; f < 2; ++f) {
                    acc[f][g] = __builtin_amdgcn_mfma_f32_16x16x32_bf16(ah[f * 2 + ks], bh, acc[f][g], 0, 0, 0);
                    acc[f][g] = __builtin_amdgcn_mfma_f32_16x16x32_bf16(ah[f * 2 + ks], bl, acc[f][g], 0, 0, 0);
                    acc[f][g] = __builtin_amdgcn_mfma_f32_16x16x32_bf16(al[f * 2 + ks], bh, acc[f][g], 0, 0, 0);
                }
            }
        }
    };

    float4 Af[8];
    bf16x8 ah[4], al[4];
    ldA(0, Af);
    cvtA(Af, ah, al);
    for (int kt = 0; kt < K; kt += 64) {
        float4 An[8];
        bool more = (kt + 64) < K;
        if (more) ldA(kt + 64, An);   // in flight during compute
        compute(kt, ah, al);
        if (more) cvtA(An, ah, al);   // waits on loads after MFMAs
    }

    // ---- epilogue: C/D layout col=lane&15, row=(lane>>4)*4+reg (m89-verified)
    int rbase = m0 + wave * 32 + (lane >> 4) * 4;
#pragma unroll
    for (int f = 0; f < 2; ++f) {
#pragma unroll
        for (int r = 0; r < 4; ++r) {
            int row = rbase + f * 16 + r;
            if (row >= M) continue;
            float* yr = Y + (size_t)row * ldy + ln;
#pragma unroll
            for (int g = 0; g < 8; ++g) {
                float v = acc[f][g][r] + bv[g];
                if (relu) v = fmaxf(v, 0.f);
                yr[g * 16] = v;
            }
        }
    }
}

// ---------------- host orchestration ----------------
extern "C" void kernel_launch(void* const* d_in, const int* in_sizes, int n_in,
                              void* d_out, int out_size, void* d_ws, size_t ws_size,
                              hipStream_t stream) {
    const float* emb[4] = {(const float*)d_in[0], (const float*)d_in[1],
                           (const float*)d_in[2], (const float*)d_in[3]};
    const float* W1_l = (const float*)d_in[4];
    const float* b1 = (const float*)d_in[5];
    const float* W1_r = (const float*)d_in[6];
    const float* W2_l = (const float*)d_in[7];
    const float* b2 = (const float*)d_in[8];
    const float* W2_r = (const float*)d_in[9];
    const float* ew[8];
    for (int i = 0; i < 8; ++i) ew[i] = (const float*)d_in[10 + i];
    const int* ei_buys = (const int*)d_in[18];
    const int* ei_sea = (const int*)d_in[19];
    const int* ei_mat = (const int*)d_in[20];
    const int* ei_in = (const int*)d_in[21];

    const int NT[4] = {NUSER, NPROD, NCAT, NQRY};
    const int rowOff[4] = {0, NUSER, NUSER + NPROD, NUSER + NPROD + NCAT};
    const int nrelD[4] = {2, 3, 1, 2};
    const int wtPre[4] = {0, 49152, 114688, 147456};

    struct RelT { int s, d, slot, E; const int* src; const int* dst; const float* w; };
    // slot assignment must match wt_build relsD: user{1,3} product{0,4,7} cat{6} query{2,5}
    RelT rel[8] = {
        {0, 1, 0, EBUYS,   ei_buys,          ei_buys + EBUYS,  ew[0]},  // t0
        {1, 0, 0, EBUYS,   ei_buys + EBUYS,  ei_buys,          ew[1]},  // t1
        {0, 3, 0, ESEARCH, ei_sea,           ei_sea + ESEARCH, ew[2]},  // t2
        {3, 0, 1, ESEARCH, ei_sea + ESEARCH, ei_sea,           ew[3]},  // t3
        {3, 1, 1, EMATCH,  ei_mat,           ei_mat + EMATCH,  ew[4]},  // t4
        {1, 3, 1, EMATCH,  ei_mat + EMATCH,  ei_mat,           ew[5]},  // t5
        {1, 2, 0, EIN,     ei_in,            ei_in + EIN,      ew[6]},  // t6
        {2, 1, 2, EIN,     ei_in + EIN,      ei_in,            ew[7]},  // t7
    };

    // ---- workspace carve ----
    char* p = (char*)d_ws;
    auto carve = [&](size_t bytes) {
        char* r = p;
        p += (bytes + 255) & ~(size_t)255;
        return r;
    };
    int* offs[8];
    for (int t = 0; t < 8; ++t) offs[t] = (int*)carve(((size_t)NT[rel[t].d] + 1) * 4);
    size_t fillTot = 0;
    for (int t = 0; t < 8; ++t) fillTot += (size_t)NT[rel[t].d];
    int* fillBase = (int*)carve(fillTot * 4);
    int* fill[8];
    {
        size_t o = 0;
        for (int t = 0; t < 8; ++t) { fill[t] = fillBase + o; o += NT[rel[t].d]; }
    }
    size_t Etot = 0;
    int eoff[8];
    for (int t = 0; t < 8; ++t) { eoff[t] = (int)Etot; Etot += rel[t].E; }
    int* csr_src = (int*)carve(Etot * 4);
    float* csr_w = (float*)carve(Etot * 4);
    int* bsums = (int*)carve(64 * 4);
    unsigned short* WH = (unsigned short*)carve((size_t)2 * 196608 * 2);
    unsigned short* WL = (unsigned short*)carve((size_t)2 * 196608 * 2);
    float* bsum = (float*)carve((size_t)8 * 128 * 4);
    // concat aggregate buffer: per dst type, [n_d][128*k_d], all types resident
    size_t aoff[4];
    size_t atot = 0;
    for (int d = 0; d < 4; ++d) {
        aoff[d] = atot;
        atot += (size_t)NT[d] * 128 * nrelD[d];
    }
    float* aggbuf = (float*)carve(atot * 4);  // ~410.6 MB

    // ---- CSR build (once, reused by both layers) ----
    hipMemsetAsync(fillBase, 0, fillTot * 4, stream);
    for (int t = 0; t < 8; ++t)
        count_kernel<<<(rel[t].E + 255) / 256, 256, 0, stream>>>(rel[t].dst, rel[t].E, fill[t]);
    for (int t = 0; t < 8; ++t) {
        int n = NT[rel[t].d];
        int nb = (n + 4095) / 4096;
        scan_partial<<<nb, 256, 0, stream>>>(fill[t], n, bsums);
        scan_bsums<<<1, 64, 0, stream>>>(bsums, nb);
        scan_final<<<nb, 256, 0, stream>>>(fill[t], n, bsums, offs[t]);
    }
    hipMemsetAsync(fillBase, 0, fillTot * 4, stream);
    for (int t = 0; t < 8; ++t)
        fill_kernel<<<(rel[t].E + 255) / 256, 256, 0, stream>>>(
            rel[t].src, rel[t].dst, rel[t].w, rel[t].E, offs[t], fill[t],
            csr_src + eoff[t], csr_w + eoff[t]);

    // ---- fused split-bf16 weights + summed bias ----
    wt_build<<<24, 256, 0, stream>>>(W1_l, b1, W1_r, W2_l, b2, W2_r, WH, WL, bsum);

    float* dout = (float*)d_out;

    // ---- two layers; layer-0 output (h) lives in d_out, layer-1 GEMM is in-place ----
    for (int layer = 0; layer < 2; ++layer) {
        // all aggregations first (layer-1 must read h before GEMMs overwrite d_out)
        for (int t = 0; t < 8; ++t) {
            int sT = rel[t].s, dT = rel[t].d, n = NT[dT];
            const float* X = layer == 0 ? emb[sT] : dout + (size_t)rowOff[sT] * 128;
            agg_kernel<<<(n + 3) / 4, 256, 0, stream>>>(
                X, 128, offs[t], csr_src + eoff[t], csr_w + eoff[t],
                aggbuf + aoff[dT] + rel[t].slot * 128, 128 * nrelD[dT], n);
        }
        // one fused MFMA GEMM per dst type
        for (int d = 0; d < 4; ++d) {
            int n = NT[d];
            const float* self = layer == 0 ? emb[d] : dout + (size_t)rowOff[d] * 128;
            size_t woff = (size_t)layer * 196608 + wtPre[d];
            gemm_fused<<<(n + 127) / 128, 256, 0, stream>>>(
                self, 128, aggbuf + aoff[d], 128 * nrelD[d],
                WH + woff, WL + woff, bsum + (size_t)(layer * 4 + d) * 128,
                dout + (size_t)rowOff[d] * 128, 128, n, (1 + nrelD[d]) * 128,
                layer == 0 ? 1 : 0);
        }
    }
}

// Round 3
// 2135.016 us; speedup vs baseline: 1.0974x; 1.0974x over previous
//
#include <hip/hip_runtime.h>

// ---------------- problem constants ----------------
#define NUSER 200000
#define NPROD 100000
#define NCAT    2000
#define NQRY   50000
#define EBUYS  500000
#define ESEARCH 300000
#define EMATCH  300000
#define EIN     100000

// type ids: 0=user 1=product 2=category 3=query
// relations t=0..7 (weight-stack index):
//  t0 user->product, t1 product->user, t2 user->query, t3 query->user,
//  t4 query->product, t5 product->query, t6 product->category, t7 category->product
// per-dst relation slots (must match wt_build's relsD):
//  user: {t1,t3}  product: {t0,t4,t7}  category: {t6}  query: {t2,t5}

// ---------------- CSR build ----------------
__global__ __launch_bounds__(256) void count_kernel(const int* __restrict__ dst, int E,
                                                    int* __restrict__ cnt) {
    int i = blockIdx.x * 256 + threadIdx.x;
    if (i < E) atomicAdd(&cnt[dst[i]], 1);
}

__global__ __launch_bounds__(256) void scan_partial(const int* __restrict__ cnt, int n,
                                                    int* __restrict__ bsums) {
    __shared__ int sd[256];
    int base = blockIdx.x * 4096;
    int s = 0;
    for (int j = threadIdx.x; j < 4096; j += 256) {
        int idx = base + j;
        s += (idx < n) ? cnt[idx] : 0;
    }
    sd[threadIdx.x] = s;
    __syncthreads();
    for (int st = 128; st > 0; st >>= 1) {
        if (threadIdx.x < st) sd[threadIdx.x] += sd[threadIdx.x + st];
        __syncthreads();
    }
    if (threadIdx.x == 0) bsums[blockIdx.x] = sd[0];
}

__global__ __launch_bounds__(64) void scan_bsums(int* __restrict__ bs, int nb) {
    int lane = threadIdx.x;
    int orig = (lane < nb) ? bs[lane] : 0;
    int v = orig;
    for (int off = 1; off < 64; off <<= 1) {
        int t = __shfl_up(v, off);
        if (lane >= off) v += t;
    }
    if (lane < nb) bs[lane] = v - orig;  // exclusive
}

__global__ __launch_bounds__(256) void scan_final(const int* __restrict__ cnt, int n,
                                                  const int* __restrict__ bsums,
                                                  int* __restrict__ offs) {
    __shared__ int tsum[256];
    int base = blockIdx.x * 4096;
    int tid = threadIdx.x;
    int local[16];
    int s = 0;
#pragma unroll
    for (int j = 0; j < 16; ++j) {
        int idx = base + tid * 16 + j;
        int v = (idx < n) ? cnt[idx] : 0;
        s += v;
        local[j] = s;
    }
    tsum[tid] = s;
    __syncthreads();
    int v = s;
    for (int off = 1; off < 256; off <<= 1) {
        int t = (tid >= off) ? tsum[tid - off] : 0;
        __syncthreads();
        v += t;
        tsum[tid] = v;
        __syncthreads();
    }
    int tpre = v - s;
    int bpre = bsums[blockIdx.x];
#pragma unroll
    for (int j = 0; j < 16; ++j) {
        int idx = base + tid * 16 + j;
        if (idx < n) offs[idx + 1] = bpre + tpre + local[j];
    }
    if (blockIdx.x == 0 && tid == 0) offs[0] = 0;
}

__global__ __launch_bounds__(256) void fill_kernel(const int* __restrict__ src,
                                                   const int* __restrict__ dst,
                                                   const float* __restrict__ w, int E,
                                                   const int* __restrict__ offs,
                                                   int* __restrict__ fill,
                                                   int* __restrict__ csr_src,
                                                   float* __restrict__ csr_w) {
    int i = blockIdx.x * 256 + threadIdx.x;
    if (i >= E) return;
    int d = dst[i];
    int slot = offs[d] + atomicAdd(&fill[d], 1);
    csr_src[slot] = src[i];
    csr_w[slot] = w[i];
}

// ---------------- f32 -> bf16 hi/lo split helpers ----------------
// hi = truncated top 16 bits (exact bf16); lo = bf16(trunc) of residual.
// a ~= hi + lo with relative error ~2^-16; dropped lo*lo term in the GEMM is
// ~2^-16 relative => result is f32-equivalent for this problem's magnitudes.
__device__ __forceinline__ unsigned pk_hi(float a, float b) {
    return (__float_as_uint(b) & 0xffff0000u) | (__float_as_uint(a) >> 16);
}
__device__ __forceinline__ float f32_trunc(float a) {
    return __uint_as_float(__float_as_uint(a) & 0xffff0000u);
}

typedef short bf16x8 __attribute__((ext_vector_type(8)));
typedef float f32x4 __attribute__((ext_vector_type(4)));

__device__ __forceinline__ bf16x8 pack_hi8(const float4& a, const float4& b) {
    union { unsigned u[4]; bf16x8 v; } r;
    r.u[0] = pk_hi(a.x, a.y);
    r.u[1] = pk_hi(a.z, a.w);
    r.u[2] = pk_hi(b.x, b.y);
    r.u[3] = pk_hi(b.z, b.w);
    return r.v;
}
__device__ __forceinline__ bf16x8 pack_lo8(const float4& a, const float4& b) {
    union { unsigned u[4]; bf16x8 v; } r;
    r.u[0] = pk_hi(a.x - f32_trunc(a.x), a.y - f32_trunc(a.y));
    r.u[1] = pk_hi(a.z - f32_trunc(a.z), a.w - f32_trunc(a.w));
    r.u[2] = pk_hi(b.x - f32_trunc(b.x), b.y - f32_trunc(b.y));
    r.u[3] = pk_hi(b.z - f32_trunc(b.z), b.w - f32_trunc(b.w));
    return r.v;
}

// ---------------- fused weight build ----------------
// Produces bf16 hi/lo planes of the concat-K B matrix, stored as a sequence of
// 64-k tiles per (layer,dst): tile t is 128n x 64k = 8192 shorts, PRE-SWIZZLED:
//   elem (n, kk) lives at tile*8192 + ((n*64 + kk) ^ ((n&7)<<3))
// so the GEMM can copy it LINEARLY into LDS and read conflict-free ds_read_b128
// with the same XOR (Guideline 21: source perm == read perm).
// Block 0 of k (s=0) is sum_t Wl[t]; block s>=1 is Wr[rels[s-1]].
// Also writes bsum[(l*4+d)*128].
__global__ __launch_bounds__(256) void wt_build(const float* __restrict__ W1_l,
                                                const float* __restrict__ b1,
                                                const float* __restrict__ W1_r,
                                                const float* __restrict__ W2_l,
                                                const float* __restrict__ b2,
                                                const float* __restrict__ W2_r,
                                                unsigned short* __restrict__ WH,
                                                unsigned short* __restrict__ WL,
                                                float* __restrict__ bsum) {
    const int relsD[4][3] = {{1, 3, -1}, {0, 4, 7}, {6, -1, -1}, {2, 5, -1}};
    const int nrelD[4] = {2, 3, 1, 2};
    const int pre[4] = {0, 49152, 114688, 147456};  // elements, per-layer prefix
    int bid = blockIdx.x;
    int l = bid / 12, r = bid % 12;
    int d, s;
    if (r < 3) { d = 0; s = r; }
    else if (r < 7) { d = 1; s = r - 3; }
    else if (r < 9) { d = 2; s = r - 7; }
    else { d = 3; s = r - 9; }
    const float* Wl = l ? W2_l : W1_l;
    const float* Wr = l ? W2_r : W1_r;
    const float* bb = l ? b2 : b1;
    size_t base = (size_t)l * 196608 + pre[d];
    if (s == 0 && threadIdx.x < 128) {
        float acc = 0.f;
        for (int j = 0; j < nrelD[d]; ++j) acc += bb[relsD[d][j] * 128 + threadIdx.x];
        bsum[(l * 4 + d) * 128 + threadIdx.x] = acc;
    }
    // 128 n x 128 in elements; 8-elem (16B) chunks: 2048 chunks / 256 threads = 8 iters
    for (int p = 0; p < 8; ++p) {
        int c = threadIdx.x + p * 256;
        int n = c >> 4, ic = (c & 15) * 8;
        float e[8];
        if (s == 0) {
#pragma unroll
            for (int q = 0; q < 8; ++q) e[q] = 0.f;
            for (int j = 0; j < nrelD[d]; ++j) {
                const float* wsrc = Wl + relsD[d][j] * 16384 + n * 128 + ic;
#pragma unroll
                for (int q = 0; q < 8; ++q) e[q] += wsrc[q];
            }
        } else {
            const float* wsrc = Wr + relsD[d][s - 1] * 16384 + n * 128 + ic;
#pragma unroll
            for (int q = 0; q < 8; ++q) e[q] = wsrc[q];
        }
        uint4 hi, lo;
        hi.x = pk_hi(e[0], e[1]); hi.y = pk_hi(e[2], e[3]);
        hi.z = pk_hi(e[4], e[5]); hi.w = pk_hi(e[6], e[7]);
        float lv[8];
#pragma unroll
        for (int q = 0; q < 8; ++q) lv[q] = e[q] - f32_trunc(e[q]);
        lo.x = pk_hi(lv[0], lv[1]); lo.y = pk_hi(lv[2], lv[3]);
        lo.z = pk_hi(lv[4], lv[5]); lo.w = pk_hi(lv[6], lv[7]);
        // global k = s*128 + ic; 64-k tile index and offset within it:
        int tile = s * 2 + (ic >> 6);
        int kk = ic & 63;
        size_t go = base + (size_t)tile * 8192 + (size_t)(((n * 64 + kk) ^ ((n & 7) << 3)));
        *(uint4*)(WH + go) = hi;
        *(uint4*)(WL + go) = lo;
    }
}

// ---------------- CSR gather-reduce (scatter-mean) into concat-slot layout ----------
// 32 lanes per dst row (float4 each), 2 rows per wave, 8 rows per block.
// (Round-1 version — measured better than the 64-lane x4-unrolled variant.)
__global__ __launch_bounds__(256) void agg_kernel(const float* __restrict__ X, int ldx,
                                                  const int* __restrict__ offs,
                                                  const int* __restrict__ csr_src,
                                                  const float* __restrict__ csr_w,
                                                  float* __restrict__ out, int ldo,
                                                  int n_dst) {
    int row = blockIdx.x * 8 + (threadIdx.x >> 5);
    if (row >= n_dst) return;
    int lane = threadIdx.x & 31;
    int b = offs[row], e = offs[row + 1];
    float4 a = {0.f, 0.f, 0.f, 0.f};
    for (int i = b; i < e; ++i) {
        int s = csr_src[i];
        float w = csr_w[i];
        const float4 v = *(const float4*)(X + (size_t)s * ldx + lane * 4);
        a.x += w * v.x;
        a.y += w * v.y;
        a.z += w * v.z;
        a.w += w * v.w;
    }
    float inv = (e > b) ? 1.f / (float)(e - b) : 0.f;
    a.x *= inv; a.y *= inv; a.z *= inv; a.w *= inv;
    *(float4*)(out + (size_t)row * ldo + lane * 4) = a;
}

// ---------------- fused concat-K MFMA GEMM: Y = relu?([self|agg] @ W^T + bias) ------
// Split-bf16 (hi/lo) f32 emulation on v_mfma_f32_16x16x32_bf16:
//   C = Ah*Bh + Ah*Bl + Al*Bh  (f32 accumulate; dropped Al*Bl ~ 2^-16 rel)
// A (streamed, zero cross-wave reuse): global -> reg, packed in-reg. No A LDS.
// B (reused by all 4 waves): staged in LDS once per block per k-tile as a PURE COPY
// of the pre-split, pre-swizzled WH/WL tiles (no pack VALU, no transpose).
// LDS 32 KiB; __launch_bounds__(256,3) targets 3 waves/SIMD (12 waves/CU).
__global__ __launch_bounds__(256, 3) void gemm_fused(const float* __restrict__ Xself, int lds_,
                                                     const float* __restrict__ Xagg, int lda_,
                                                     const unsigned short* __restrict__ WH,
                                                     const unsigned short* __restrict__ WL,
                                                     const float* __restrict__ bias,
                                                     float* __restrict__ Y, int ldy,
                                                     int M, int K, int relu) {
    __shared__ unsigned short sBh[8192];  // one 64-k B tile, hi plane, swizzled
    __shared__ unsigned short sBl[8192];  // lo plane
    int tid = threadIdx.x;
    int lane = tid & 63;
    int wave = tid >> 6;  // 0..3
    int m0 = blockIdx.x * 128;
    int ln = lane & 15;
    int kq = (lane >> 4) * 8;   // lane's k-offset within a 32-k step
    int rowA = wave * 32 + ln;  // tile-row for f=0; f=1 adds 16

    f32x4 acc[2][8] = {};  // [m-frag][n-frag]

    float bv[8];
#pragma unroll
    for (int g = 0; g < 8; ++g) bv[g] = bias[g * 16 + ln];

    int nt = K >> 6;
    for (int t = 0; t < nt; ++t) {
        int kt = t << 6;
        const float* Xsrc;
        int ldx, kc0;
        if (kt < 128) { Xsrc = Xself; ldx = lds_; kc0 = kt; }
        else { Xsrc = Xagg; ldx = lda_; kc0 = kt - 128; }
        const unsigned short* wht = WH + (size_t)t * 8192;
        const unsigned short* wlt = WL + (size_t)t * 8192;
        __syncthreads();  // all waves done reading previous tile's LDS
        // ---- issue B tile loads (global -> reg, linear copy of swizzled tile)
        uint4 rh[4], rl[4];
#pragma unroll
        for (int p = 0; p < 4; ++p) {
            rh[p] = *(const uint4*)(wht + (size_t)(tid + p * 256) * 8);
            rl[p] = *(const uint4*)(wlt + (size_t)(tid + p * 256) * 8);
        }
        // ---- issue A loads (global -> reg); consumed after the barrier
        float4 Af[8];
#pragma unroll
        for (int f = 0; f < 2; ++f) {
            int gm = m0 + rowA + f * 16;
            const float* pr = Xsrc + (size_t)gm * ldx + kc0 + kq;
#pragma unroll
            for (int ks = 0; ks < 2; ++ks) {
                float4 v0 = {0.f, 0.f, 0.f, 0.f}, v1 = {0.f, 0.f, 0.f, 0.f};
                if (gm < M) {
                    v0 = *(const float4*)(pr + ks * 32);
                    v1 = *(const float4*)(pr + ks * 32 + 4);
                }
                Af[(f * 2 + ks) * 2 + 0] = v0;
                Af[(f * 2 + ks) * 2 + 1] = v1;
            }
        }
        // ---- write B tile to LDS (linear; conflict-free: tid*16B consecutive)
#pragma unroll
        for (int p = 0; p < 4; ++p) {
            *(uint4*)&sBh[(size_t)(tid + p * 256) * 8] = rh[p];
            *(uint4*)&sBl[(size_t)(tid + p * 256) * 8] = rl[p];
        }
        __syncthreads();  // B tile staged
        // ---- pack A to bf16 hi/lo in-reg
        bf16x8 ah[4], al[4];
#pragma unroll
        for (int j = 0; j < 4; ++j) {
            ah[j] = pack_hi8(Af[j * 2], Af[j * 2 + 1]);
            al[j] = pack_lo8(Af[j * 2], Af[j * 2 + 1]);
        }
        // ---- compute: 2 k-steps of 32; B frags from LDS (swizzled, conflict-free)
#pragma unroll
        for (int ks = 0; ks < 2; ++ks) {
#pragma unroll
            for (int g = 0; g < 8; ++g) {
                int sidx = ((g * 16 + ln) * 64 + ks * 32 + kq) ^ ((ln & 7) << 3);
                bf16x8 bh = *(const bf16x8*)&sBh[sidx];
                bf16x8 bl = *(const bf16x8*)&sBl[sidx];
#pragma unroll
                for (int f = 0; f < 2; ++f) {
                    acc[f][g] = __builtin_amdgcn_mfma_f32_16x16x32_bf16(ah[f * 2 + ks], bh, acc[f][g], 0, 0, 0);
                    acc[f][g] = __builtin_amdgcn_mfma_f32_16x16x32_bf16(ah[f * 2 + ks], bl, acc[f][g], 0, 0, 0);
                    acc[f][g] = __builtin_amdgcn_mfma_f32_16x16x32_bf16(al[f * 2 + ks], bh, acc[f][g], 0, 0, 0);
                }
            }
        }
    }
    // ---- epilogue: C/D layout col=lane&15, row=(lane>>4)*4+reg (m89-verified)
    int rbase = m0 + wave * 32 + (lane >> 4) * 4;
#pragma unroll
    for (int f = 0; f < 2; ++f) {
#pragma unroll
        for (int r = 0; r < 4; ++r) {
            int row = rbase + f * 16 + r;
            if (row >= M) continue;
            float* yr = Y + (size_t)row * ldy + ln;
#pragma unroll
            for (int g = 0; g < 8; ++g) {
                float v = acc[f][g][r] + bv[g];
                if (relu) v = fmaxf(v, 0.f);
                yr[g * 16] = v;
            }
        }
    }
}

// ---------------- host orchestration ----------------
extern "C" void kernel_launch(void* const* d_in, const int* in_sizes, int n_in,
                              void* d_out, int out_size, void* d_ws, size_t ws_size,
                              hipStream_t stream) {
    const float* emb[4] = {(const float*)d_in[0], (const float*)d_in[1],
                           (const float*)d_in[2], (const float*)d_in[3]};
    const float* W1_l = (const float*)d_in[4];
    const float* b1 = (const float*)d_in[5];
    const float* W1_r = (const float*)d_in[6];
    const float* W2_l = (const float*)d_in[7];
    const float* b2 = (const float*)d_in[8];
    const float* W2_r = (const float*)d_in[9];
    const float* ew[8];
    for (int i = 0; i < 8; ++i) ew[i] = (const float*)d_in[10 + i];
    const int* ei_buys = (const int*)d_in[18];
    const int* ei_sea = (const int*)d_in[19];
    const int* ei_mat = (const int*)d_in[20];
    const int* ei_in = (const int*)d_in[21];

    const int NT[4] = {NUSER, NPROD, NCAT, NQRY};
    const int rowOff[4] = {0, NUSER, NUSER + NPROD, NUSER + NPROD + NCAT};
    const int nrelD[4] = {2, 3, 1, 2};
    const int wtPre[4] = {0, 49152, 114688, 147456};

    struct RelT { int s, d, slot, E; const int* src; const int* dst; const float* w; };
    // slot assignment must match wt_build relsD: user{1,3} product{0,4,7} cat{6} query{2,5}
    RelT rel[8] = {
        {0, 1, 0, EBUYS,   ei_buys,          ei_buys + EBUYS,  ew[0]},  // t0
        {1, 0, 0, EBUYS,   ei_buys + EBUYS,  ei_buys,          ew[1]},  // t1
        {0, 3, 0, ESEARCH, ei_sea,           ei_sea + ESEARCH, ew[2]},  // t2
        {3, 0, 1, ESEARCH, ei_sea + ESEARCH, ei_sea,           ew[3]},  // t3
        {3, 1, 1, EMATCH,  ei_mat,           ei_mat + EMATCH,  ew[4]},  // t4
        {1, 3, 1, EMATCH,  ei_mat + EMATCH,  ei_mat,           ew[5]},  // t5
        {1, 2, 0, EIN,     ei_in,            ei_in + EIN,      ew[6]},  // t6
        {2, 1, 2, EIN,     ei_in + EIN,      ei_in,            ew[7]},  // t7
    };

    // ---- workspace carve ----
    char* p = (char*)d_ws;
    auto carve = [&](size_t bytes) {
        char* r = p;
        p += (bytes + 255) & ~(size_t)255;
        return r;
    };
    int* offs[8];
    for (int t = 0; t < 8; ++t) offs[t] = (int*)carve(((size_t)NT[rel[t].d] + 1) * 4);
    size_t fillTot = 0;
    for (int t = 0; t < 8; ++t) fillTot += (size_t)NT[rel[t].d];
    int* fillBase = (int*)carve(fillTot * 4);
    int* fill[8];
    {
        size_t o = 0;
        for (int t = 0; t < 8; ++t) { fill[t] = fillBase + o; o += NT[rel[t].d]; }
    }
    size_t Etot = 0;
    int eoff[8];
    for (int t = 0; t < 8; ++t) { eoff[t] = (int)Etot; Etot += rel[t].E; }
    int* csr_src = (int*)carve(Etot * 4);
    float* csr_w = (float*)carve(Etot * 4);
    int* bsums = (int*)carve(64 * 4);
    unsigned short* WH = (unsigned short*)carve((size_t)2 * 196608 * 2);
    unsigned short* WL = (unsigned short*)carve((size_t)2 * 196608 * 2);
    float* bsum = (float*)carve((size_t)8 * 128 * 4);
    // concat aggregate buffer: per dst type, [n_d][128*k_d], all types resident
    size_t aoff[4];
    size_t atot = 0;
    for (int d = 0; d < 4; ++d) {
        aoff[d] = atot;
        atot += (size_t)NT[d] * 128 * nrelD[d];
    }
    float* aggbuf = (float*)carve(atot * 4);  // ~410.6 MB

    // ---- CSR build (once, reused by both layers) ----
    hipMemsetAsync(fillBase, 0, fillTot * 4, stream);
    for (int t = 0; t < 8; ++t)
        count_kernel<<<(rel[t].E + 255) / 256, 256, 0, stream>>>(rel[t].dst, rel[t].E, fill[t]);
    for (int t = 0; t < 8; ++t) {
        int n = NT[rel[t].d];
        int nb = (n + 4095) / 4096;
        scan_partial<<<nb, 256, 0, stream>>>(fill[t], n, bsums);
        scan_bsums<<<1, 64, 0, stream>>>(bsums, nb);
        scan_final<<<nb, 256, 0, stream>>>(fill[t], n, bsums, offs[t]);
    }
    hipMemsetAsync(fillBase, 0, fillTot * 4, stream);
    for (int t = 0; t < 8; ++t)
        fill_kernel<<<(rel[t].E + 255) / 256, 256, 0, stream>>>(
            rel[t].src, rel[t].dst, rel[t].w, rel[t].E, offs[t], fill[t],
            csr_src + eoff[t], csr_w + eoff[t]);

    // ---- fused split-bf16 weights (tiled + swizzled) + summed bias ----
    wt_build<<<24, 256, 0, stream>>>(W1_l, b1, W1_r, W2_l, b2, W2_r, WH, WL, bsum);

    float* dout = (float*)d_out;

    // ---- two layers; layer-0 output (h) lives in d_out, layer-1 GEMM is in-place ----
    for (int layer = 0; layer < 2; ++layer) {
        // all aggregations first (layer-1 must read h before GEMMs overwrite d_out)
        for (int t = 0; t < 8; ++t) {
            int sT = rel[t].s, dT = rel[t].d, n = NT[dT];
            const float* X = layer == 0 ? emb[sT] : dout + (size_t)rowOff[sT] * 128;
            agg_kernel<<<(n + 7) / 8, 256, 0, stream>>>(
                X, 128, offs[t], csr_src + eoff[t], csr_w + eoff[t],
                aggbuf + aoff[dT] + rel[t].slot * 128, 128 * nrelD[dT], n);
        }
        // one fused MFMA GEMM per dst type
        for (int d = 0; d < 4; ++d) {
            int n = NT[d];
            const float* self = layer == 0 ? emb[d] : dout + (size_t)rowOff[d] * 128;
            size_t woff = (size_t)layer * 196608 + wtPre[d];
            gemm_fused<<<(n + 127) / 128, 256, 0, stream>>>(
                self, 128, aggbuf + aoff[d], 128 * nrelD[d],
                WH + woff, WL + woff, bsum + (size_t)(layer * 4 + d) * 128,
                dout + (size_t)rowOff[d] * 128, 128, n, (1 + nrelD[d]) * 128,
                layer == 0 ? 1 : 0);
        }
    }
}

// Round 4
// 2070.627 us; speedup vs baseline: 1.1316x; 1.0311x over previous
//
#include <hip/hip_runtime.h>

// ---------------- problem constants ----------------
#define NUSER 200000
#define NPROD 100000
#define NCAT    2000
#define NQRY   50000
#define EBUYS  500000
#define ESEARCH 300000
#define EMATCH  300000
#define EIN     100000

// type ids: 0=user 1=product 2=category 3=query
// relations t=0..7 (weight-stack index):
//  t0 user->product, t1 product->user, t2 user->query, t3 query->user,
//  t4 query->product, t5 product->query, t6 product->category, t7 category->product
// per-dst relation slots (must match wt_build's relsD):
//  user: {t1,t3}  product: {t0,t4,t7}  category: {t6}  query: {t2,t5}

// ---------------- CSR build ----------------
__global__ __launch_bounds__(256) void count_kernel(const int* __restrict__ dst, int E,
                                                    int* __restrict__ cnt) {
    int i = blockIdx.x * 256 + threadIdx.x;
    if (i < E) atomicAdd(&cnt[dst[i]], 1);
}

__global__ __launch_bounds__(256) void scan_partial(const int* __restrict__ cnt, int n,
                                                    int* __restrict__ bsums) {
    __shared__ int sd[256];
    int base = blockIdx.x * 4096;
    int s = 0;
    for (int j = threadIdx.x; j < 4096; j += 256) {
        int idx = base + j;
        s += (idx < n) ? cnt[idx] : 0;
    }
    sd[threadIdx.x] = s;
    __syncthreads();
    for (int st = 128; st > 0; st >>= 1) {
        if (threadIdx.x < st) sd[threadIdx.x] += sd[threadIdx.x + st];
        __syncthreads();
    }
    if (threadIdx.x == 0) bsums[blockIdx.x] = sd[0];
}

__global__ __launch_bounds__(64) void scan_bsums(int* __restrict__ bs, int nb) {
    int lane = threadIdx.x;
    int orig = (lane < nb) ? bs[lane] : 0;
    int v = orig;
    for (int off = 1; off < 64; off <<= 1) {
        int t = __shfl_up(v, off);
        if (lane >= off) v += t;
    }
    if (lane < nb) bs[lane] = v - orig;  // exclusive
}

__global__ __launch_bounds__(256) void scan_final(const int* __restrict__ cnt, int n,
                                                  const int* __restrict__ bsums,
                                                  int* __restrict__ offs) {
    __shared__ int tsum[256];
    int base = blockIdx.x * 4096;
    int tid = threadIdx.x;
    int local[16];
    int s = 0;
#pragma unroll
    for (int j = 0; j < 16; ++j) {
        int idx = base + tid * 16 + j;
        int v = (idx < n) ? cnt[idx] : 0;
        s += v;
        local[j] = s;
    }
    tsum[tid] = s;
    __syncthreads();
    int v = s;
    for (int off = 1; off < 256; off <<= 1) {
        int t = (tid >= off) ? tsum[tid - off] : 0;
        __syncthreads();
        v += t;
        tsum[tid] = v;
        __syncthreads();
    }
    int tpre = v - s;
    int bpre = bsums[blockIdx.x];
#pragma unroll
    for (int j = 0; j < 16; ++j) {
        int idx = base + tid * 16 + j;
        if (idx < n) offs[idx + 1] = bpre + tpre + local[j];
    }
    if (blockIdx.x == 0 && tid == 0) offs[0] = 0;
}

__global__ __launch_bounds__(256) void fill_kernel(const int* __restrict__ src,
                                                   const int* __restrict__ dst,
                                                   const float* __restrict__ w, int E,
                                                   const int* __restrict__ offs,
                                                   int* __restrict__ fill,
                                                   int* __restrict__ csr_src,
                                                   float* __restrict__ csr_w) {
    int i = blockIdx.x * 256 + threadIdx.x;
    if (i >= E) return;
    int d = dst[i];
    int slot = offs[d] + atomicAdd(&fill[d], 1);
    csr_src[slot] = src[i];
    csr_w[slot] = w[i];
}

// ---------------- f32 -> bf16 hi/lo split helpers ----------------
// hi = truncated top 16 bits (exact bf16); lo = bf16(trunc) of residual.
// a ~= hi + lo with relative error ~2^-16; dropped lo*lo term in the GEMM is
// ~2^-16 relative => result is f32-equivalent for this problem's magnitudes.
__device__ __forceinline__ unsigned pk_hi(float a, float b) {
    return (__float_as_uint(b) & 0xffff0000u) | (__float_as_uint(a) >> 16);
}
__device__ __forceinline__ float f32_trunc(float a) {
    return __uint_as_float(__float_as_uint(a) & 0xffff0000u);
}

typedef short bf16x8 __attribute__((ext_vector_type(8)));
typedef float f32x4 __attribute__((ext_vector_type(4)));

__device__ __forceinline__ bf16x8 pack_hi8(const float4& a, const float4& b) {
    union { unsigned u[4]; bf16x8 v; } r;
    r.u[0] = pk_hi(a.x, a.y);
    r.u[1] = pk_hi(a.z, a.w);
    r.u[2] = pk_hi(b.x, b.y);
    r.u[3] = pk_hi(b.z, b.w);
    return r.v;
}
__device__ __forceinline__ bf16x8 pack_lo8(const float4& a, const float4& b) {
    union { unsigned u[4]; bf16x8 v; } r;
    r.u[0] = pk_hi(a.x - f32_trunc(a.x), a.y - f32_trunc(a.y));
    r.u[1] = pk_hi(a.z - f32_trunc(a.z), a.w - f32_trunc(a.w));
    r.u[2] = pk_hi(b.x - f32_trunc(b.x), b.y - f32_trunc(b.y));
    r.u[3] = pk_hi(b.z - f32_trunc(b.z), b.w - f32_trunc(b.w));
    return r.v;
}

// ---------------- fused weight build ----------------
// Produces bf16 hi/lo planes of the concat-K B matrix, stored as a sequence of
// 64-k tiles per (layer,dst): tile t is 128n x 64k = 8192 shorts, PRE-SWIZZLED:
//   elem (n, kk) lives at tile*8192 + ((n*64 + kk) ^ ((n&7)<<3))
// so the GEMM can copy it LINEARLY into LDS and read conflict-free ds_read_b128
// with the same XOR (Guideline 21: source perm == read perm).
// Block 0 of k (s=0) is sum_t Wl[t]; block s>=1 is Wr[rels[s-1]].
// Also writes bsum[(l*4+d)*128].
__global__ __launch_bounds__(256) void wt_build(const float* __restrict__ W1_l,
                                                const float* __restrict__ b1,
                                                const float* __restrict__ W1_r,
                                                const float* __restrict__ W2_l,
                                                const float* __restrict__ b2,
                                                const float* __restrict__ W2_r,
                                                unsigned short* __restrict__ WH,
                                                unsigned short* __restrict__ WL,
                                                float* __restrict__ bsum) {
    const int relsD[4][3] = {{1, 3, -1}, {0, 4, 7}, {6, -1, -1}, {2, 5, -1}};
    const int nrelD[4] = {2, 3, 1, 2};
    const int pre[4] = {0, 49152, 114688, 147456};  // elements, per-layer prefix
    int bid = blockIdx.x;
    int l = bid / 12, r = bid % 12;
    int d, s;
    if (r < 3) { d = 0; s = r; }
    else if (r < 7) { d = 1; s = r - 3; }
    else if (r < 9) { d = 2; s = r - 7; }
    else { d = 3; s = r - 9; }
    const float* Wl = l ? W2_l : W1_l;
    const float* Wr = l ? W2_r : W1_r;
    const float* bb = l ? b2 : b1;
    size_t base = (size_t)l * 196608 + pre[d];
    if (s == 0 && threadIdx.x < 128) {
        float acc = 0.f;
        for (int j = 0; j < nrelD[d]; ++j) acc += bb[relsD[d][j] * 128 + threadIdx.x];
        bsum[(l * 4 + d) * 128 + threadIdx.x] = acc;
    }
    // 128 n x 128 in elements; 8-elem (16B) chunks: 2048 chunks / 256 threads = 8 iters
    for (int p = 0; p < 8; ++p) {
        int c = threadIdx.x + p * 256;
        int n = c >> 4, ic = (c & 15) * 8;
        float e[8];
        if (s == 0) {
#pragma unroll
            for (int q = 0; q < 8; ++q) e[q] = 0.f;
            for (int j = 0; j < nrelD[d]; ++j) {
                const float* wsrc = Wl + relsD[d][j] * 16384 + n * 128 + ic;
#pragma unroll
                for (int q = 0; q < 8; ++q) e[q] += wsrc[q];
            }
        } else {
            const float* wsrc = Wr + relsD[d][s - 1] * 16384 + n * 128 + ic;
#pragma unroll
            for (int q = 0; q < 8; ++q) e[q] = wsrc[q];
        }
        uint4 hi, lo;
        hi.x = pk_hi(e[0], e[1]); hi.y = pk_hi(e[2], e[3]);
        hi.z = pk_hi(e[4], e[5]); hi.w = pk_hi(e[6], e[7]);
        float lv[8];
#pragma unroll
        for (int q = 0; q < 8; ++q) lv[q] = e[q] - f32_trunc(e[q]);
        lo.x = pk_hi(lv[0], lv[1]); lo.y = pk_hi(lv[2], lv[3]);
        lo.z = pk_hi(lv[4], lv[5]); lo.w = pk_hi(lv[6], lv[7]);
        // global k = s*128 + ic; 64-k tile index and offset within it:
        int tile = s * 2 + (ic >> 6);
        int kk = ic & 63;
        size_t go = base + (size_t)tile * 8192 + (size_t)(((n * 64 + kk) ^ ((n & 7) << 3)));
        *(uint4*)(WH + go) = hi;
        *(uint4*)(WL + go) = lo;
    }
}

// ---------------- CSR gather-reduce (scatter-mean) into concat-slot layout ----------
// 8 lanes per dst row, each lane owns 16 consecutive floats (4x float4):
//   - MLP=4 per edge (4 independent gather loads per lane)
//   - 32 rows per 256-thread block -> 256 rows/CU in flight (4x round-3)
//   - next edge's index/weight prefetched during current edge's gather+FMA
// Per-column accumulation stays in ascending CSR order with a single accumulator
// => bitwise-identical to the previous agg versions.
__global__ __launch_bounds__(256) void agg_kernel(const float* __restrict__ X, int ldx,
                                                  const int* __restrict__ offs,
                                                  const int* __restrict__ csr_src,
                                                  const float* __restrict__ csr_w,
                                                  float* __restrict__ out, int ldo,
                                                  int n_dst) {
    int row = blockIdx.x * 32 + (threadIdx.x >> 3);
    if (row >= n_dst) return;
    int col = (threadIdx.x & 7) * 16;  // this lane's 16-float slice
    int b = offs[row], e = offs[row + 1];
    float4 a0 = {0.f, 0.f, 0.f, 0.f}, a1 = a0, a2 = a0, a3 = a0;
    int i = b;
    if (i < e) {
        int s = csr_src[i];
        float w = csr_w[i];
        for (;;) {
            const float* xp = X + (size_t)s * ldx + col;
            float4 v0 = *(const float4*)(xp + 0);
            float4 v1 = *(const float4*)(xp + 4);
            float4 v2 = *(const float4*)(xp + 8);
            float4 v3 = *(const float4*)(xp + 12);
            ++i;
            bool more = i < e;
            int sn = 0;
            float wn = 0.f;
            if (more) {  // prefetch next index/weight under the gather latency
                sn = csr_src[i];
                wn = csr_w[i];
            }
            a0.x += w * v0.x; a0.y += w * v0.y; a0.z += w * v0.z; a0.w += w * v0.w;
            a1.x += w * v1.x; a1.y += w * v1.y; a1.z += w * v1.z; a1.w += w * v1.w;
            a2.x += w * v2.x; a2.y += w * v2.y; a2.z += w * v2.z; a2.w += w * v2.w;
            a3.x += w * v3.x; a3.y += w * v3.y; a3.z += w * v3.z; a3.w += w * v3.w;
            if (!more) break;
            s = sn;
            w = wn;
        }
    }
    float inv = (e > b) ? 1.f / (float)(e - b) : 0.f;
    a0.x *= inv; a0.y *= inv; a0.z *= inv; a0.w *= inv;
    a1.x *= inv; a1.y *= inv; a1.z *= inv; a1.w *= inv;
    a2.x *= inv; a2.y *= inv; a2.z *= inv; a2.w *= inv;
    a3.x *= inv; a3.y *= inv; a3.z *= inv; a3.w *= inv;
    float* op = out + (size_t)row * ldo + col;
    *(float4*)(op + 0) = a0;
    *(float4*)(op + 4) = a1;
    *(float4*)(op + 8) = a2;
    *(float4*)(op + 12) = a3;
}

// ---------------- fused concat-K MFMA GEMM: Y = relu?([self|agg] @ W^T + bias) ------
// Split-bf16 (hi/lo) f32 emulation on v_mfma_f32_16x16x32_bf16:
//   C = Ah*Bh + Ah*Bl + Al*Bh  (f32 accumulate; dropped Al*Bl ~ 2^-16 rel)
// A (streamed, zero cross-wave reuse): global -> reg, packed in-reg. No A LDS.
// B (reused by all 4 waves): staged in LDS once per block per k-tile as a PURE COPY
// of the pre-split, pre-swizzled WH/WL tiles (no pack VALU, no transpose).
// LDS 32 KiB; __launch_bounds__(256,3) targets 3 waves/SIMD (12 waves/CU).
__global__ __launch_bounds__(256, 3) void gemm_fused(const float* __restrict__ Xself, int lds_,
                                                     const float* __restrict__ Xagg, int lda_,
                                                     const unsigned short* __restrict__ WH,
                                                     const unsigned short* __restrict__ WL,
                                                     const float* __restrict__ bias,
                                                     float* __restrict__ Y, int ldy,
                                                     int M, int K, int relu) {
    __shared__ unsigned short sBh[8192];  // one 64-k B tile, hi plane, swizzled
    __shared__ unsigned short sBl[8192];  // lo plane
    int tid = threadIdx.x;
    int lane = tid & 63;
    int wave = tid >> 6;  // 0..3
    int m0 = blockIdx.x * 128;
    int ln = lane & 15;
    int kq = (lane >> 4) * 8;   // lane's k-offset within a 32-k step
    int rowA = wave * 32 + ln;  // tile-row for f=0; f=1 adds 16

    f32x4 acc[2][8] = {};  // [m-frag][n-frag]

    float bv[8];
#pragma unroll
    for (int g = 0; g < 8; ++g) bv[g] = bias[g * 16 + ln];

    int nt = K >> 6;
    for (int t = 0; t < nt; ++t) {
        int kt = t << 6;
        const float* Xsrc;
        int ldx, kc0;
        if (kt < 128) { Xsrc = Xself; ldx = lds_; kc0 = kt; }
        else { Xsrc = Xagg; ldx = lda_; kc0 = kt - 128; }
        const unsigned short* wht = WH + (size_t)t * 8192;
        const unsigned short* wlt = WL + (size_t)t * 8192;
        __syncthreads();  // all waves done reading previous tile's LDS
        // ---- issue B tile loads (global -> reg, linear copy of swizzled tile)
        uint4 rh[4], rl[4];
#pragma unroll
        for (int p = 0; p < 4; ++p) {
            rh[p] = *(const uint4*)(wht + (size_t)(tid + p * 256) * 8);
            rl[p] = *(const uint4*)(wlt + (size_t)(tid + p * 256) * 8);
        }
        // ---- issue A loads (global -> reg); consumed after the barrier
        float4 Af[8];
#pragma unroll
        for (int f = 0; f < 2; ++f) {
            int gm = m0 + rowA + f * 16;
            const float* pr = Xsrc + (size_t)gm * ldx + kc0 + kq;
#pragma unroll
            for (int ks = 0; ks < 2; ++ks) {
                float4 v0 = {0.f, 0.f, 0.f, 0.f}, v1 = {0.f, 0.f, 0.f, 0.f};
                if (gm < M) {
                    v0 = *(const float4*)(pr + ks * 32);
                    v1 = *(const float4*)(pr + ks * 32 + 4);
                }
                Af[(f * 2 + ks) * 2 + 0] = v0;
                Af[(f * 2 + ks) * 2 + 1] = v1;
            }
        }
        // ---- write B tile to LDS (linear; conflict-free: tid*16B consecutive)
#pragma unroll
        for (int p = 0; p < 4; ++p) {
            *(uint4*)&sBh[(size_t)(tid + p * 256) * 8] = rh[p];
            *(uint4*)&sBl[(size_t)(tid + p * 256) * 8] = rl[p];
        }
        __syncthreads();  // B tile staged
        // ---- pack A to bf16 hi/lo in-reg
        bf16x8 ah[4], al[4];
#pragma unroll
        for (int j = 0; j < 4; ++j) {
            ah[j] = pack_hi8(Af[j * 2], Af[j * 2 + 1]);
            al[j] = pack_lo8(Af[j * 2], Af[j * 2 + 1]);
        }
        // ---- compute: 2 k-steps of 32; B frags from LDS (swizzled, conflict-free)
#pragma unroll
        for (int ks = 0; ks < 2; ++ks) {
#pragma unroll
            for (int g = 0; g < 8; ++g) {
                int sidx = ((g * 16 + ln) * 64 + ks * 32 + kq) ^ ((ln & 7) << 3);
                bf16x8 bh = *(const bf16x8*)&sBh[sidx];
                bf16x8 bl = *(const bf16x8*)&sBl[sidx];
#pragma unroll
                for (int f = 0; f < 2; ++f) {
                    acc[f][g] = __builtin_amdgcn_mfma_f32_16x16x32_bf16(ah[f * 2 + ks], bh, acc[f][g], 0, 0, 0);
                    acc[f][g] = __builtin_amdgcn_mfma_f32_16x16x32_bf16(ah[f * 2 + ks], bl, acc[f][g], 0, 0, 0);
                    acc[f][g] = __builtin_amdgcn_mfma_f32_16x16x32_bf16(al[f * 2 + ks], bh, acc[f][g], 0, 0, 0);
                }
            }
        }
    }
    // ---- epilogue: C/D layout col=lane&15, row=(lane>>4)*4+reg (m89-verified)
    int rbase = m0 + wave * 32 + (lane >> 4) * 4;
#pragma unroll
    for (int f = 0; f < 2; ++f) {
#pragma unroll
        for (int r = 0; r < 4; ++r) {
            int row = rbase + f * 16 + r;
            if (row >= M) continue;
            float* yr = Y + (size_t)row * ldy + ln;
#pragma unroll
            for (int g = 0; g < 8; ++g) {
                float v = acc[f][g][r] + bv[g];
                if (relu) v = fmaxf(v, 0.f);
                yr[g * 16] = v;
            }
        }
    }
}

// ---------------- host orchestration ----------------
extern "C" void kernel_launch(void* const* d_in, const int* in_sizes, int n_in,
                              void* d_out, int out_size, void* d_ws, size_t ws_size,
                              hipStream_t stream) {
    const float* emb[4] = {(const float*)d_in[0], (const float*)d_in[1],
                           (const float*)d_in[2], (const float*)d_in[3]};
    const float* W1_l = (const float*)d_in[4];
    const float* b1 = (const float*)d_in[5];
    const float* W1_r = (const float*)d_in[6];
    const float* W2_l = (const float*)d_in[7];
    const float* b2 = (const float*)d_in[8];
    const float* W2_r = (const float*)d_in[9];
    const float* ew[8];
    for (int i = 0; i < 8; ++i) ew[i] = (const float*)d_in[10 + i];
    const int* ei_buys = (const int*)d_in[18];
    const int* ei_sea = (const int*)d_in[19];
    const int* ei_mat = (const int*)d_in[20];
    const int* ei_in = (const int*)d_in[21];

    const int NT[4] = {NUSER, NPROD, NCAT, NQRY};
    const int rowOff[4] = {0, NUSER, NUSER + NPROD, NUSER + NPROD + NCAT};
    const int nrelD[4] = {2, 3, 1, 2};
    const int wtPre[4] = {0, 49152, 114688, 147456};

    struct RelT { int s, d, slot, E; const int* src; const int* dst; const float* w; };
    // slot assignment must match wt_build relsD: user{1,3} product{0,4,7} cat{6} query{2,5}
    RelT rel[8] = {
        {0, 1, 0, EBUYS,   ei_buys,          ei_buys + EBUYS,  ew[0]},  // t0
        {1, 0, 0, EBUYS,   ei_buys + EBUYS,  ei_buys,          ew[1]},  // t1
        {0, 3, 0, ESEARCH, ei_sea,           ei_sea + ESEARCH, ew[2]},  // t2
        {3, 0, 1, ESEARCH, ei_sea + ESEARCH, ei_sea,           ew[3]},  // t3
        {3, 1, 1, EMATCH,  ei_mat,           ei_mat + EMATCH,  ew[4]},  // t4
        {1, 3, 1, EMATCH,  ei_mat + EMATCH,  ei_mat,           ew[5]},  // t5
        {1, 2, 0, EIN,     ei_in,            ei_in + EIN,      ew[6]},  // t6
        {2, 1, 2, EIN,     ei_in + EIN,      ei_in,            ew[7]},  // t7
    };

    // ---- workspace carve ----
    char* p = (char*)d_ws;
    auto carve = [&](size_t bytes) {
        char* r = p;
        p += (bytes + 255) & ~(size_t)255;
        return r;
    };
    int* offs[8];
    for (int t = 0; t < 8; ++t) offs[t] = (int*)carve(((size_t)NT[rel[t].d] + 1) * 4);
    size_t fillTot = 0;
    for (int t = 0; t < 8; ++t) fillTot += (size_t)NT[rel[t].d];
    int* fillBase = (int*)carve(fillTot * 4);
    int* fill[8];
    {
        size_t o = 0;
        for (int t = 0; t < 8; ++t) { fill[t] = fillBase + o; o += NT[rel[t].d]; }
    }
    size_t Etot = 0;
    int eoff[8];
    for (int t = 0; t < 8; ++t) { eoff[t] = (int)Etot; Etot += rel[t].E; }
    int* csr_src = (int*)carve(Etot * 4);
    float* csr_w = (float*)carve(Etot * 4);
    int* bsums = (int*)carve(64 * 4);
    unsigned short* WH = (unsigned short*)carve((size_t)2 * 196608 * 2);
    unsigned short* WL = (unsigned short*)carve((size_t)2 * 196608 * 2);
    float* bsum = (float*)carve((size_t)8 * 128 * 4);
    // concat aggregate buffer: per dst type, [n_d][128*k_d], all types resident
    size_t aoff[4];
    size_t atot = 0;
    for (int d = 0; d < 4; ++d) {
        aoff[d] = atot;
        atot += (size_t)NT[d] * 128 * nrelD[d];
    }
    float* aggbuf = (float*)carve(atot * 4);  // ~410.6 MB

    // ---- CSR build (once, reused by both layers) ----
    hipMemsetAsync(fillBase, 0, fillTot * 4, stream);
    for (int t = 0; t < 8; ++t)
        count_kernel<<<(rel[t].E + 255) / 256, 256, 0, stream>>>(rel[t].dst, rel[t].E, fill[t]);
    for (int t = 0; t < 8; ++t) {
        int n = NT[rel[t].d];
        int nb = (n + 4095) / 4096;
        scan_partial<<<nb, 256, 0, stream>>>(fill[t], n, bsums);
        scan_bsums<<<1, 64, 0, stream>>>(bsums, nb);
        scan_final<<<nb, 256, 0, stream>>>(fill[t], n, bsums, offs[t]);
    }
    hipMemsetAsync(fillBase, 0, fillTot * 4, stream);
    for (int t = 0; t < 8; ++t)
        fill_kernel<<<(rel[t].E + 255) / 256, 256, 0, stream>>>(
            rel[t].src, rel[t].dst, rel[t].w, rel[t].E, offs[t], fill[t],
            csr_src + eoff[t], csr_w + eoff[t]);

    // ---- fused split-bf16 weights (tiled + swizzled) + summed bias ----
    wt_build<<<24, 256, 0, stream>>>(W1_l, b1, W1_r, W2_l, b2, W2_r, WH, WL, bsum);

    float* dout = (float*)d_out;

    // ---- two layers; layer-0 output (h) lives in d_out, layer-1 GEMM is in-place ----
    for (int layer = 0; layer < 2; ++layer) {
        // all aggregations first (layer-1 must read h before GEMMs overwrite d_out)
        for (int t = 0; t < 8; ++t) {
            int sT = rel[t].s, dT = rel[t].d, n = NT[dT];
            const float* X = layer == 0 ? emb[sT] : dout + (size_t)rowOff[sT] * 128;
            agg_kernel<<<(n + 31) / 32, 256, 0, stream>>>(
                X, 128, offs[t], csr_src + eoff[t], csr_w + eoff[t],
                aggbuf + aoff[dT] + rel[t].slot * 128, 128 * nrelD[dT], n);
        }
        // one fused MFMA GEMM per dst type
        for (int d = 0; d < 4; ++d) {
            int n = NT[d];
            const float* self = layer == 0 ? emb[d] : dout + (size_t)rowOff[d] * 128;
            size_t woff = (size_t)layer * 196608 + wtPre[d];
            gemm_fused<<<(n + 127) / 128, 256, 0, stream>>>(
                self, 128, aggbuf + aoff[d], 128 * nrelD[d],
                WH + woff, WL + woff, bsum + (size_t)(layer * 4 + d) * 128,
                dout + (size_t)rowOff[d] * 128, 128, n, (1 + nrelD[d]) * 128,
                layer == 0 ? 1 : 0);
        }
    }
}

// Round 5
// 1960.076 us; speedup vs baseline: 1.1954x; 1.0564x over previous
//
#include <hip/hip_runtime.h>

// ---------------- problem constants ----------------
#define NUSER 200000
#define NPROD 100000
#define NCAT    2000
#define NQRY   50000
#define EBUYS  500000
#define ESEARCH 300000
#define EMATCH  300000
#define EIN     100000

// type ids: 0=user 1=product 2=category 3=query
// relations t=0..7 (weight-stack index):
//  t0 user->product, t1 product->user, t2 user->query, t3 query->user,
//  t4 query->product, t5 product->query, t6 product->category, t7 category->product
// per-dst relation slots (must match wt_build's relsD):
//  user: {t1,t3}  product: {t0,t4,t7}  category: {t6}  query: {t2,t5}

// ---------------- CSR build ----------------
__global__ __launch_bounds__(256) void count_kernel(const int* __restrict__ dst, int E,
                                                    int* __restrict__ cnt) {
    int i = blockIdx.x * 256 + threadIdx.x;
    if (i < E) atomicAdd(&cnt[dst[i]], 1);
}

__global__ __launch_bounds__(256) void scan_partial(const int* __restrict__ cnt, int n,
                                                    int* __restrict__ bsums) {
    __shared__ int sd[256];
    int base = blockIdx.x * 4096;
    int s = 0;
    for (int j = threadIdx.x; j < 4096; j += 256) {
        int idx = base + j;
        s += (idx < n) ? cnt[idx] : 0;
    }
    sd[threadIdx.x] = s;
    __syncthreads();
    for (int st = 128; st > 0; st >>= 1) {
        if (threadIdx.x < st) sd[threadIdx.x] += sd[threadIdx.x + st];
        __syncthreads();
    }
    if (threadIdx.x == 0) bsums[blockIdx.x] = sd[0];
}

__global__ __launch_bounds__(64) void scan_bsums(int* __restrict__ bs, int nb) {
    int lane = threadIdx.x;
    int orig = (lane < nb) ? bs[lane] : 0;
    int v = orig;
    for (int off = 1; off < 64; off <<= 1) {
        int t = __shfl_up(v, off);
        if (lane >= off) v += t;
    }
    if (lane < nb) bs[lane] = v - orig;  // exclusive
}

__global__ __launch_bounds__(256) void scan_final(const int* __restrict__ cnt, int n,
                                                  const int* __restrict__ bsums,
                                                  int* __restrict__ offs) {
    __shared__ int tsum[256];
    int base = blockIdx.x * 4096;
    int tid = threadIdx.x;
    int local[16];
    int s = 0;
#pragma unroll
    for (int j = 0; j < 16; ++j) {
        int idx = base + tid * 16 + j;
        int v = (idx < n) ? cnt[idx] : 0;
        s += v;
        local[j] = s;
    }
    tsum[tid] = s;
    __syncthreads();
    int v = s;
    for (int off = 1; off < 256; off <<= 1) {
        int t = (tid >= off) ? tsum[tid - off] : 0;
        __syncthreads();
        v += t;
        tsum[tid] = v;
        __syncthreads();
    }
    int tpre = v - s;
    int bpre = bsums[blockIdx.x];
#pragma unroll
    for (int j = 0; j < 16; ++j) {
        int idx = base + tid * 16 + j;
        if (idx < n) offs[idx + 1] = bpre + tpre + local[j];
    }
    if (blockIdx.x == 0 && tid == 0) offs[0] = 0;
}

__global__ __launch_bounds__(256) void fill_kernel(const int* __restrict__ src,
                                                   const int* __restrict__ dst,
                                                   const float* __restrict__ w, int E,
                                                   const int* __restrict__ offs,
                                                   int* __restrict__ fill,
                                                   int* __restrict__ csr_src,
                                                   float* __restrict__ csr_w) {
    int i = blockIdx.x * 256 + threadIdx.x;
    if (i >= E) return;
    int d = dst[i];
    int slot = offs[d] + atomicAdd(&fill[d], 1);
    csr_src[slot] = src[i];
    csr_w[slot] = w[i];
}

// ---------------- f32 -> bf16 hi/lo split helpers ----------------
// hi = truncated top 16 bits (exact bf16); lo = bf16(trunc) of residual.
// a ~= hi + lo with relative error ~2^-16; dropped lo*lo term in the GEMM is
// ~2^-16 relative => result is f32-equivalent for this problem's magnitudes.
__device__ __forceinline__ unsigned pk_hi(float a, float b) {
    return (__float_as_uint(b) & 0xffff0000u) | (__float_as_uint(a) >> 16);
}
__device__ __forceinline__ float f32_trunc(float a) {
    return __uint_as_float(__float_as_uint(a) & 0xffff0000u);
}

typedef short bf16x8 __attribute__((ext_vector_type(8)));
typedef float f32x4 __attribute__((ext_vector_type(4)));

__device__ __forceinline__ bf16x8 pack_hi8(const float4& a, const float4& b) {
    union { unsigned u[4]; bf16x8 v; } r;
    r.u[0] = pk_hi(a.x, a.y);
    r.u[1] = pk_hi(a.z, a.w);
    r.u[2] = pk_hi(b.x, b.y);
    r.u[3] = pk_hi(b.z, b.w);
    return r.v;
}
__device__ __forceinline__ bf16x8 pack_lo8(const float4& a, const float4& b) {
    union { unsigned u[4]; bf16x8 v; } r;
    r.u[0] = pk_hi(a.x - f32_trunc(a.x), a.y - f32_trunc(a.y));
    r.u[1] = pk_hi(a.z - f32_trunc(a.z), a.w - f32_trunc(a.w));
    r.u[2] = pk_hi(b.x - f32_trunc(b.x), b.y - f32_trunc(b.y));
    r.u[3] = pk_hi(b.z - f32_trunc(b.z), b.w - f32_trunc(b.w));
    return r.v;
}

// ---------------- fused weight build ----------------
// Produces bf16 hi/lo planes of the concat-K B matrix, stored as a sequence of
// 64-k tiles per (layer,dst): tile t is 128n x 64k = 8192 shorts, PRE-SWIZZLED:
//   elem (n, kk) lives at tile*8192 + ((n*64 + kk) ^ ((n&7)<<3))
// so the GEMM can copy it LINEARLY into LDS and read conflict-free ds_read_b128
// with the same XOR (Guideline 21: source perm == read perm).
// Block 0 of k (s=0) is sum_t Wl[t]; block s>=1 is Wr[rels[s-1]].
// Also writes bsum[(l*4+d)*128].
__global__ __launch_bounds__(256) void wt_build(const float* __restrict__ W1_l,
                                                const float* __restrict__ b1,
                                                const float* __restrict__ W1_r,
                                                const float* __restrict__ W2_l,
                                                const float* __restrict__ b2,
                                                const float* __restrict__ W2_r,
                                                unsigned short* __restrict__ WH,
                                                unsigned short* __restrict__ WL,
                                                float* __restrict__ bsum) {
    const int relsD[4][3] = {{1, 3, -1}, {0, 4, 7}, {6, -1, -1}, {2, 5, -1}};
    const int nrelD[4] = {2, 3, 1, 2};
    const int pre[4] = {0, 49152, 114688, 147456};  // elements, per-layer prefix
    int bid = blockIdx.x;
    int l = bid / 12, r = bid % 12;
    int d, s;
    if (r < 3) { d = 0; s = r; }
    else if (r < 7) { d = 1; s = r - 3; }
    else if (r < 9) { d = 2; s = r - 7; }
    else { d = 3; s = r - 9; }
    const float* Wl = l ? W2_l : W1_l;
    const float* Wr = l ? W2_r : W1_r;
    const float* bb = l ? b2 : b1;
    size_t base = (size_t)l * 196608 + pre[d];
    if (s == 0 && threadIdx.x < 128) {
        float acc = 0.f;
        for (int j = 0; j < nrelD[d]; ++j) acc += bb[relsD[d][j] * 128 + threadIdx.x];
        bsum[(l * 4 + d) * 128 + threadIdx.x] = acc;
    }
    // 128 n x 128 in elements; 8-elem (16B) chunks: 2048 chunks / 256 threads = 8 iters
    for (int p = 0; p < 8; ++p) {
        int c = threadIdx.x + p * 256;
        int n = c >> 4, ic = (c & 15) * 8;
        float e[8];
        if (s == 0) {
#pragma unroll
            for (int q = 0; q < 8; ++q) e[q] = 0.f;
            for (int j = 0; j < nrelD[d]; ++j) {
                const float* wsrc = Wl + relsD[d][j] * 16384 + n * 128 + ic;
#pragma unroll
                for (int q = 0; q < 8; ++q) e[q] += wsrc[q];
            }
        } else {
            const float* wsrc = Wr + relsD[d][s - 1] * 16384 + n * 128 + ic;
#pragma unroll
            for (int q = 0; q < 8; ++q) e[q] = wsrc[q];
        }
        uint4 hi, lo;
        hi.x = pk_hi(e[0], e[1]); hi.y = pk_hi(e[2], e[3]);
        hi.z = pk_hi(e[4], e[5]); hi.w = pk_hi(e[6], e[7]);
        float lv[8];
#pragma unroll
        for (int q = 0; q < 8; ++q) lv[q] = e[q] - f32_trunc(e[q]);
        lo.x = pk_hi(lv[0], lv[1]); lo.y = pk_hi(lv[2], lv[3]);
        lo.z = pk_hi(lv[4], lv[5]); lo.w = pk_hi(lv[6], lv[7]);
        // global k = s*128 + ic; 64-k tile index and offset within it:
        int tile = s * 2 + (ic >> 6);
        int kk = ic & 63;
        size_t go = base + (size_t)tile * 8192 + (size_t)(((n * 64 + kk) ^ ((n & 7) << 3)));
        *(uint4*)(WH + go) = hi;
        *(uint4*)(WL + go) = lo;
    }
}

// ---------------- per-relation CSR args for the fused GEMM ----------------
struct RelArg {
    const int* offs;    // [n_dst+1]
    const int* csr;     // src indices, CSR order
    const float* w;     // edge weights, CSR order
    const float* X;     // source-type feature rows [n_src][128]
};

// ---------------- fused gather + concat-K MFMA GEMM ----------------
// Y = relu?([self | mean-agg(rel0) | mean-agg(rel1) | ...] @ W^T + bias)
// Split-bf16 (hi/lo) f32 emulation on v_mfma_f32_16x16x32_bf16:
//   C = Ah*Bh + Ah*Bl + Al*Bh  (f32 accumulate; dropped Al*Bl ~ 2^-16 rel)
// A for self tiles: streamed global->reg. A for agg tiles: COMPUTED IN-REG by
// iterating the row's CSR edges (scatter-mean fused into the GEMM) — same
// per-column ascending accumulation + *inv as the old agg_kernel => bitwise-
// identical output, but the 820 MB/layer aggbuf round-trip is gone.
// B (reused by all 4 waves): staged in LDS per k-tile as a PURE COPY of the
// pre-split, pre-swizzled WH/WL tiles. LDS 32 KiB.
__global__ __launch_bounds__(256, 3) void gemm_fused(const float* __restrict__ Xself, int lds_,
                                                     RelArg R0, RelArg R1, RelArg R2,
                                                     const unsigned short* __restrict__ WH,
                                                     const unsigned short* __restrict__ WL,
                                                     const float* __restrict__ bias,
                                                     float* __restrict__ Y, int ldy,
                                                     int M, int K, int relu) {
    __shared__ unsigned short sBh[8192];  // one 64-k B tile, hi plane, swizzled
    __shared__ unsigned short sBl[8192];  // lo plane
    int tid = threadIdx.x;
    int lane = tid & 63;
    int wave = tid >> 6;  // 0..3
    int m0 = blockIdx.x * 128;
    int ln = lane & 15;
    int kq = (lane >> 4) * 8;   // lane's k-offset within a 32-k step
    int rowA = wave * 32 + ln;  // tile-row for f=0; f=1 adds 16

    f32x4 acc[2][8] = {};  // [m-frag][n-frag]

    float bv[8];
#pragma unroll
    for (int g = 0; g < 8; ++g) bv[g] = bias[g * 16 + ln];

    int nt = K >> 6;
    for (int t = 0; t < nt; ++t) {
        const unsigned short* wht = WH + (size_t)t * 8192;
        const unsigned short* wlt = WL + (size_t)t * 8192;
        __syncthreads();  // all waves done reading previous tile's LDS
        // ---- issue B tile loads (global -> reg, linear copy of swizzled tile)
        uint4 rh[4], rl[4];
#pragma unroll
        for (int p = 0; p < 4; ++p) {
            rh[p] = *(const uint4*)(wht + (size_t)(tid + p * 256) * 8);
            rl[p] = *(const uint4*)(wlt + (size_t)(tid + p * 256) * 8);
        }
        // ---- produce A fragments: Af[(f*2+ks)*2+half] covers cols kq+ks*32+half*4..+4
        float4 Af[8];
        if (t < 2) {
            // self tile: stream
            int kc0 = t * 64;
#pragma unroll
            for (int f = 0; f < 2; ++f) {
                int gm = m0 + rowA + f * 16;
                const float* pr = Xself + (size_t)gm * lds_ + kc0 + kq;
#pragma unroll
                for (int ks = 0; ks < 2; ++ks) {
                    float4 v0 = {0.f, 0.f, 0.f, 0.f}, v1 = {0.f, 0.f, 0.f, 0.f};
                    if (gm < M) {
                        v0 = *(const float4*)(pr + ks * 32);
                        v1 = *(const float4*)(pr + ks * 32 + 4);
                    }
                    Af[(f * 2 + ks) * 2 + 0] = v0;
                    Af[(f * 2 + ks) * 2 + 1] = v1;
                }
            }
        } else {
            // agg tile: fused CSR gather-mean (scatter-mean of source rows)
            int r = (t - 2) >> 1;
            int kc0r = ((t - 2) & 1) * 64;
            RelArg R = (r == 0) ? R0 : ((r == 1) ? R1 : R2);
#pragma unroll
            for (int f = 0; f < 2; ++f) {
                int gm = m0 + rowA + f * 16;
                float4 a0 = {0.f, 0.f, 0.f, 0.f}, a1 = a0, a2 = a0, a3 = a0;
                if (gm < M) {
                    int b = R.offs[gm], e = R.offs[gm + 1];
                    int i = b;
                    if (i < e) {
                        int s = R.csr[i];
                        float w = R.w[i];
                        for (;;) {
                            const float* xp = R.X + (size_t)s * 128 + kc0r + kq;
                            float4 v0 = *(const float4*)(xp + 0);
                            float4 v1 = *(const float4*)(xp + 4);
                            float4 v2 = *(const float4*)(xp + 32);
                            float4 v3 = *(const float4*)(xp + 36);
                            ++i;
                            bool more = i < e;
                            int sn = 0;
                            float wn = 0.f;
                            if (more) {  // prefetch next idx/weight under gather latency
                                sn = R.csr[i];
                                wn = R.w[i];
                            }
                            a0.x += w * v0.x; a0.y += w * v0.y; a0.z += w * v0.z; a0.w += w * v0.w;
                            a1.x += w * v1.x; a1.y += w * v1.y; a1.z += w * v1.z; a1.w += w * v1.w;
                            a2.x += w * v2.x; a2.y += w * v2.y; a2.z += w * v2.z; a2.w += w * v2.w;
                            a3.x += w * v3.x; a3.y += w * v3.y; a3.z += w * v3.z; a3.w += w * v3.w;
                            if (!more) break;
                            s = sn;
                            w = wn;
                        }
                        float inv = 1.f / (float)(e - b);
                        a0.x *= inv; a0.y *= inv; a0.z *= inv; a0.w *= inv;
                        a1.x *= inv; a1.y *= inv; a1.z *= inv; a1.w *= inv;
                        a2.x *= inv; a2.y *= inv; a2.z *= inv; a2.w *= inv;
                        a3.x *= inv; a3.y *= inv; a3.z *= inv; a3.w *= inv;
                    }
                }
                Af[(f * 2 + 0) * 2 + 0] = a0;
                Af[(f * 2 + 0) * 2 + 1] = a1;
                Af[(f * 2 + 1) * 2 + 0] = a2;
                Af[(f * 2 + 1) * 2 + 1] = a3;
            }
        }
        // ---- write B tile to LDS (linear; conflict-free: tid*16B consecutive)
#pragma unroll
        for (int p = 0; p < 4; ++p) {
            *(uint4*)&sBh[(size_t)(tid + p * 256) * 8] = rh[p];
            *(uint4*)&sBl[(size_t)(tid + p * 256) * 8] = rl[p];
        }
        __syncthreads();  // B tile staged
        // ---- pack A to bf16 hi/lo in-reg
        bf16x8 ah[4], al[4];
#pragma unroll
        for (int j = 0; j < 4; ++j) {
            ah[j] = pack_hi8(Af[j * 2], Af[j * 2 + 1]);
            al[j] = pack_lo8(Af[j * 2], Af[j * 2 + 1]);
        }
        // ---- compute: 2 k-steps of 32; B frags from LDS (swizzled, conflict-free)
#pragma unroll
        for (int ks = 0; ks < 2; ++ks) {
#pragma unroll
            for (int g = 0; g < 8; ++g) {
                int sidx = ((g * 16 + ln) * 64 + ks * 32 + kq) ^ ((ln & 7) << 3);
                bf16x8 bh = *(const bf16x8*)&sBh[sidx];
                bf16x8 bl = *(const bf16x8*)&sBl[sidx];
#pragma unroll
                for (int f = 0; f < 2; ++f) {
                    acc[f][g] = __builtin_amdgcn_mfma_f32_16x16x32_bf16(ah[f * 2 + ks], bh, acc[f][g], 0, 0, 0);
                    acc[f][g] = __builtin_amdgcn_mfma_f32_16x16x32_bf16(ah[f * 2 + ks], bl, acc[f][g], 0, 0, 0);
                    acc[f][g] = __builtin_amdgcn_mfma_f32_16x16x32_bf16(al[f * 2 + ks], bh, acc[f][g], 0, 0, 0);
                }
            }
        }
    }
    // ---- epilogue: C/D layout col=lane&15, row=(lane>>4)*4+reg (m89-verified)
    int rbase = m0 + wave * 32 + (lane >> 4) * 4;
#pragma unroll
    for (int f = 0; f < 2; ++f) {
#pragma unroll
        for (int r = 0; r < 4; ++r) {
            int row = rbase + f * 16 + r;
            if (row >= M) continue;
            float* yr = Y + (size_t)row * ldy + ln;
#pragma unroll
            for (int g = 0; g < 8; ++g) {
                float v = acc[f][g][r] + bv[g];
                if (relu) v = fmaxf(v, 0.f);
                yr[g * 16] = v;
            }
        }
    }
}

// ---------------- host orchestration ----------------
extern "C" void kernel_launch(void* const* d_in, const int* in_sizes, int n_in,
                              void* d_out, int out_size, void* d_ws, size_t ws_size,
                              hipStream_t stream) {
    const float* emb[4] = {(const float*)d_in[0], (const float*)d_in[1],
                           (const float*)d_in[2], (const float*)d_in[3]};
    const float* W1_l = (const float*)d_in[4];
    const float* b1 = (const float*)d_in[5];
    const float* W1_r = (const float*)d_in[6];
    const float* W2_l = (const float*)d_in[7];
    const float* b2 = (const float*)d_in[8];
    const float* W2_r = (const float*)d_in[9];
    const float* ew[8];
    for (int i = 0; i < 8; ++i) ew[i] = (const float*)d_in[10 + i];
    const int* ei_buys = (const int*)d_in[18];
    const int* ei_sea = (const int*)d_in[19];
    const int* ei_mat = (const int*)d_in[20];
    const int* ei_in = (const int*)d_in[21];

    const int NT[4] = {NUSER, NPROD, NCAT, NQRY};
    const int rowOff[4] = {0, NUSER, NUSER + NPROD, NUSER + NPROD + NCAT};
    const int nrelD[4] = {2, 3, 1, 2};
    const int wtPre[4] = {0, 49152, 114688, 147456};

    struct RelT { int s, d, slot, E; const int* src; const int* dst; const float* w; };
    // slot assignment must match wt_build relsD: user{1,3} product{0,4,7} cat{6} query{2,5}
    RelT rel[8] = {
        {0, 1, 0, EBUYS,   ei_buys,          ei_buys + EBUYS,  ew[0]},  // t0
        {1, 0, 0, EBUYS,   ei_buys + EBUYS,  ei_buys,          ew[1]},  // t1
        {0, 3, 0, ESEARCH, ei_sea,           ei_sea + ESEARCH, ew[2]},  // t2
        {3, 0, 1, ESEARCH, ei_sea + ESEARCH, ei_sea,           ew[3]},  // t3
        {3, 1, 1, EMATCH,  ei_mat,           ei_mat + EMATCH,  ew[4]},  // t4
        {1, 3, 1, EMATCH,  ei_mat + EMATCH,  ei_mat,           ew[5]},  // t5
        {1, 2, 0, EIN,     ei_in,            ei_in + EIN,      ew[6]},  // t6
        {2, 1, 2, EIN,     ei_in + EIN,      ei_in,            ew[7]},  // t7
    };

    // ---- workspace carve ----
    char* p = (char*)d_ws;
    auto carve = [&](size_t bytes) {
        char* r = p;
        p += (bytes + 255) & ~(size_t)255;
        return r;
    };
    int* offs[8];
    for (int t = 0; t < 8; ++t) offs[t] = (int*)carve(((size_t)NT[rel[t].d] + 1) * 4);
    size_t fillTot = 0;
    for (int t = 0; t < 8; ++t) fillTot += (size_t)NT[rel[t].d];
    int* fillBase = (int*)carve(fillTot * 4);
    int* fill[8];
    {
        size_t o = 0;
        for (int t = 0; t < 8; ++t) { fill[t] = fillBase + o; o += NT[rel[t].d]; }
    }
    size_t Etot = 0;
    int eoff[8];
    for (int t = 0; t < 8; ++t) { eoff[t] = (int)Etot; Etot += rel[t].E; }
    int* csr_src = (int*)carve(Etot * 4);
    float* csr_w = (float*)carve(Etot * 4);
    int* bsums = (int*)carve(64 * 4);
    unsigned short* WH = (unsigned short*)carve((size_t)2 * 196608 * 2);
    unsigned short* WL = (unsigned short*)carve((size_t)2 * 196608 * 2);
    float* bsum = (float*)carve((size_t)8 * 128 * 4);
    // layer-0 hidden state h (all 4 types stacked): 352k x 128 f32 = ~180 MB
    float* hbuf = (float*)carve((size_t)(NUSER + NPROD + NCAT + NQRY) * 128 * 4);

    // ---- CSR build (once, reused by both layers) ----
    hipMemsetAsync(fillBase, 0, fillTot * 4, stream);
    for (int t = 0; t < 8; ++t)
        count_kernel<<<(rel[t].E + 255) / 256, 256, 0, stream>>>(rel[t].dst, rel[t].E, fill[t]);
    for (int t = 0; t < 8; ++t) {
        int n = NT[rel[t].d];
        int nb = (n + 4095) / 4096;
        scan_partial<<<nb, 256, 0, stream>>>(fill[t], n, bsums);
        scan_bsums<<<1, 64, 0, stream>>>(bsums, nb);
        scan_final<<<nb, 256, 0, stream>>>(fill[t], n, bsums, offs[t]);
    }
    hipMemsetAsync(fillBase, 0, fillTot * 4, stream);
    for (int t = 0; t < 8; ++t)
        fill_kernel<<<(rel[t].E + 255) / 256, 256, 0, stream>>>(
            rel[t].src, rel[t].dst, rel[t].w, rel[t].E, offs[t], fill[t],
            csr_src + eoff[t], csr_w + eoff[t]);

    // ---- fused split-bf16 weights (tiled + swizzled) + summed bias ----
    wt_build<<<24, 256, 0, stream>>>(W1_l, b1, W1_r, W2_l, b2, W2_r, WH, WL, bsum);

    float* dout = (float*)d_out;

    // ---- two layers; layer 0 writes hbuf, layer 1 gathers from hbuf, writes d_out ----
    for (int layer = 0; layer < 2; ++layer) {
        for (int d = 0; d < 4; ++d) {
            int n = NT[d];
            const float* self = layer == 0 ? emb[d] : hbuf + (size_t)rowOff[d] * 128;
            float* Yd = (layer == 0 ? hbuf : dout) + (size_t)rowOff[d] * 128;
            RelArg RA[3];
            int nr = 0;
            for (int t = 0; t < 8; ++t) {
                if (rel[t].d != d) continue;
                RelArg a;
                a.offs = offs[t];
                a.csr = csr_src + eoff[t];
                a.w = csr_w + eoff[t];
                a.X = layer == 0 ? emb[rel[t].s] : hbuf + (size_t)rowOff[rel[t].s] * 128;
                RA[rel[t].slot] = a;
                ++nr;
            }
            for (int s2 = nr; s2 < 3; ++s2) RA[s2] = RA[0];  // unused slots (never read)
            size_t woff = (size_t)layer * 196608 + wtPre[d];
            gemm_fused<<<(n + 127) / 128, 256, 0, stream>>>(
                self, 128, RA[0], RA[1], RA[2],
                WH + woff, WL + woff, bsum + (size_t)(layer * 4 + d) * 128,
                Yd, 128, n, (1 + nrelD[d]) * 128,
                layer == 0 ? 1 : 0);
        }
    }
}